// Round 6
// baseline (27.088 us; speedup 1.0000x reference)
//
#include <hip/hip_runtime.h>

// 3x3 VALID correlation on 4096x4096 fp32 -> 4094x4094 fp32, + bias.
// out[r][c] = sum_{kh,kw} X[r+kh][c+kw] * W[kh][kw] + bias (no kernel flip).
//
// Lane owns 4 adjacent cols (c = base + 4*lane); thread computes R=8 rows.
// Per input row: one float4 load [c,c+4) (16B-aligned) + one float2 [c+4,c+6).
// All 20 loads issued up front for MLP (round-4/5 showed latency-bound
// behavior: VALUBusy ~6%, BW well under the 6.3 TB/s ceiling).
// Stores: two float2 per row (16B stores would be misaligned on odd rows,
// since OW*4 = 16376 is 8 mod 16). Plain cached stores (NT stores caused
// 2.1x write amplification in round 3).
// Edges handled by clamping load addresses; clamped garbage only feeds
// accumulators whose output row/col >= 4094, masked at store time.

constexpr int Hin = 4096;
constexpr int Win = 4096;
constexpr int OH  = 4094;
constexpr int OW  = 4094;

constexpr int R = 8;   // output rows per thread
// lane: 4 cols; wave: 256 cols; block (256 thr): 1024 cols x 8 rows
// grid: 4 col strips x 512 row blocks = 2048 blocks (divisible by 8)

__global__ __launch_bounds__(256, 4) void conv3x3_kernel(
    const float* __restrict__ X, const float* __restrict__ Wt,
    const float* __restrict__ B, float* __restrict__ Out)
{
    // XCD-chunked swizzle: 2048 blocks -> each XCD gets 256 consecutive
    // row-blocks of one col strip (good L2 halo reuse).
    int nb = gridDim.x;
    int b  = blockIdx.x;
    int b2 = (b & 7) * (nb >> 3) + (b >> 3);

    int bx   = b2 >> 9;                 // 0..3   col strip (1024 cols)
    int by   = b2 & 511;                // 0..511 row block
    int wave = threadIdx.x >> 6;
    int lane = threadIdx.x & 63;

    int c  = bx * 1024 + wave * 256 + 4 * lane;  // out col base (mult of 4)
    int r0 = by * R;

    // edge window [c+4, c+6); clamp for the rightmost lane (c = 4092)
    int ec = (c + 4 <= Win - 2) ? (c + 4) : (Win - 2);

    // ---- preload all input rows: 20 outstanding coalesced loads ----
    float4 q[R + 2];
    float2 e[R + 2];
#pragma unroll
    for (int ir = 0; ir < R + 2; ++ir) {
        int rr = r0 + ir;
        if (rr > Hin - 1) rr = Hin - 1;          // feeds only masked rows
        const float* row = X + (size_t)rr * Win;
        q[ir] = *reinterpret_cast<const float4*>(row + c);   // 16B aligned
        e[ir] = *reinterpret_cast<const float2*>(row + ec);  // 8B aligned
    }

    float w[9];
#pragma unroll
    for (int i = 0; i < 9; ++i) w[i] = Wt[i];
    const float bias = B[0];

    float4 acc[R];
#pragma unroll
    for (int i = 0; i < R; ++i) acc[i] = make_float4(bias, bias, bias, bias);

#pragma unroll
    for (int i = 0; i < R; ++i) {
#pragma unroll
        for (int kh = 0; kh < 3; ++kh) {
            int ir = i + kh;
            float f0 = q[ir].x, f1 = q[ir].y, f2 = q[ir].z,
                  f3 = q[ir].w, f4 = e[ir].x, f5 = e[ir].y;
            float w0 = w[kh * 3 + 0], w1 = w[kh * 3 + 1], w2 = w[kh * 3 + 2];
            acc[i].x = fmaf(f0, w0, acc[i].x);
            acc[i].x = fmaf(f1, w1, acc[i].x);
            acc[i].x = fmaf(f2, w2, acc[i].x);
            acc[i].y = fmaf(f1, w0, acc[i].y);
            acc[i].y = fmaf(f2, w1, acc[i].y);
            acc[i].y = fmaf(f3, w2, acc[i].y);
            acc[i].z = fmaf(f2, w0, acc[i].z);
            acc[i].z = fmaf(f3, w1, acc[i].z);
            acc[i].z = fmaf(f4, w2, acc[i].z);
            acc[i].w = fmaf(f3, w0, acc[i].w);
            acc[i].w = fmaf(f4, w1, acc[i].w);
            acc[i].w = fmaf(f5, w2, acc[i].w);
        }
    }

    // ---- coalesced float2 stores (always 8B aligned: offset is even) ----
#pragma unroll
    for (int i = 0; i < R; ++i) {
        int orow = r0 + i;
        if (orow < OH) {
            size_t o = (size_t)orow * OW + c;
            // c <= 4092 < OW: first pair always valid
            *reinterpret_cast<float2*>(Out + o) = make_float2(acc[i].x, acc[i].y);
            if (c + 2 < OW) {     // skipped only for c = 4092
                *reinterpret_cast<float2*>(Out + o + 2) =
                    make_float2(acc[i].z, acc[i].w);
            }
        }
    }
}

extern "C" void kernel_launch(void* const* d_in, const int* in_sizes, int n_in,
                              void* d_out, int out_size, void* d_ws, size_t ws_size,
                              hipStream_t stream) {
    const float* X  = (const float*)d_in[0];
    const float* Wt = (const float*)d_in[1];
    const float* B  = (const float*)d_in[2];
    float* Out      = (float*)d_out;

    int blocks = 4 * 512;   // 2048, divisible by 8
    conv3x3_kernel<<<blocks, 256, 0, stream>>>(X, Wt, B, Out);
}

// Round 7
// 26.502 us; speedup vs baseline: 1.0221x; 1.0221x over previous
//
#include <hip/hip_runtime.h>

// 3x3 VALID correlation on 4096x4096 fp32 -> 4094x4094 fp32, + bias.
// out[r][c] = sum_{kh,kw} X[r+kh][c+kw] * W[kh][kw] + bias (no kernel flip).
//
// Round-7 change: maximize wave concurrency. Keep the perfectly-coalesced
// 2-cols/lane layout (every load/store is a contiguous 512B wave access),
// but cut per-thread state to R=4 rows (12 preloaded float2 = ~52 VGPR) and
// lift the occupancy cap to 8 waves/SIMD (32 waves/CU, 2x round 5).
// Rounds 4-6 showed latency-bound behavior (VALUBusy ~5%, occupancy 32%,
// BW ~50% of the 6.7 TB/s fill-kernel ceiling) with traffic already minimal
// (FETCH ~33MB, WRITE ~66MB).
//
// Edges handled by clamping load addresses; clamped garbage only feeds
// accumulators whose output row/col >= 4094, masked at store time.

constexpr int Hin = 4096;
constexpr int Win = 4096;
constexpr int OH  = 4094;
constexpr int OW  = 4094;

constexpr int R = 4;   // output rows per thread
// lane: 2 cols; wave: 128 cols; block (256 thr): 512 cols x 4 rows
// grid: 8 col strips x 1024 row blocks = 8192 blocks (divisible by 8)

__global__ __launch_bounds__(256, 8) void conv3x3_kernel(
    const float* __restrict__ X, const float* __restrict__ Wt,
    const float* __restrict__ B, float* __restrict__ Out)
{
    // XCD-chunked swizzle: 8192 blocks -> each XCD gets exactly one full
    // 512-col vertical strip (1024 consecutive row-blocks -> same XCD L2,
    // so the 2-row halo between vertical neighbors is L2-temporal).
    int nb = gridDim.x;
    int b  = blockIdx.x;
    int b2 = (b & 7) * (nb >> 3) + (b >> 3);

    int bx   = b2 >> 10;                // 0..7    col strip (512 cols)
    int by   = b2 & 1023;               // 0..1023 row block (4 rows)
    int wave = threadIdx.x >> 6;
    int lane = threadIdx.x & 63;

    int c  = bx * 512 + wave * 128 + 2 * lane;   // out col base (even)
    int r0 = by * R;

    // second window [c+2, c+4); clamp for the very last lane (c = 4094)
    int v1c = (c + 2 <= Win - 2) ? (c + 2) : (Win - 2);

    // ---- preload all 6 input rows: 12 outstanding coalesced float2 loads ----
    float2 v0[R + 2], v1[R + 2];
#pragma unroll
    for (int ir = 0; ir < R + 2; ++ir) {
        int rr = r0 + ir;
        if (rr > Hin - 1) rr = Hin - 1;          // feeds only masked rows
        const float* row = X + (size_t)rr * Win;
        v0[ir] = *reinterpret_cast<const float2*>(row + c);
        v1[ir] = *reinterpret_cast<const float2*>(row + v1c);
    }

    float w[9];
#pragma unroll
    for (int i = 0; i < 9; ++i) w[i] = Wt[i];
    const float bias = B[0];

    float2 acc[R];
#pragma unroll
    for (int i = 0; i < R; ++i) { acc[i].x = bias; acc[i].y = bias; }

#pragma unroll
    for (int i = 0; i < R; ++i) {
#pragma unroll
        for (int kh = 0; kh < 3; ++kh) {
            int ir = i + kh;
            float w0 = w[kh * 3 + 0], w1 = w[kh * 3 + 1], w2 = w[kh * 3 + 2];
            acc[i].x = fmaf(v0[ir].x, w0, acc[i].x);
            acc[i].x = fmaf(v0[ir].y, w1, acc[i].x);
            acc[i].x = fmaf(v1[ir].x, w2, acc[i].x);
            acc[i].y = fmaf(v0[ir].y, w0, acc[i].y);
            acc[i].y = fmaf(v1[ir].x, w1, acc[i].y);
            acc[i].y = fmaf(v1[ir].y, w2, acc[i].y);
        }
    }

    // ---- perfectly coalesced float2 stores (8B aligned: c even) ----
    if (c < OW) {                                // masks only the c = 4094 lane
#pragma unroll
        for (int i = 0; i < R; ++i) {
            int orow = r0 + i;
            if (orow < OH) {
                *reinterpret_cast<float2*>(Out + (size_t)orow * OW + c) = acc[i];
            }
        }
    }
}

extern "C" void kernel_launch(void* const* d_in, const int* in_sizes, int n_in,
                              void* d_out, int out_size, void* d_ws, size_t ws_size,
                              hipStream_t stream) {
    const float* X  = (const float*)d_in[0];
    const float* Wt = (const float*)d_in[1];
    const float* B  = (const float*)d_in[2];
    float* Out      = (float*)d_out;

    int blocks = 8 * 1024;   // 8192, divisible by 8
    conv3x3_kernel<<<blocks, 256, 0, stream>>>(X, Wt, B, Out);
}